// Round 2
// baseline (832.824 us; speedup 1.0000x reference)
//
#include <hip/hip_runtime.h>
#include <hip/hip_fp16.h>

#define E_EDGES 102400
#define N_NODES 100000
#define G_GRAPHS 64
#define D_EDGE 256
#define D_NODE 256
#define D_GLOB 128
#define KNB 4
#define D_IN 1408   // 256 + 4*256 + 128
#define H1D 512
#define H2D 512
#define H3D 256
#define LN_EPS 1e-3f

typedef _Float16 half8 __attribute__((ext_vector_type(8)));
typedef _Float16 half4v __attribute__((ext_vector_type(4)));
typedef float f32x4 __attribute__((ext_vector_type(4)));

// ---------------- prep kernels ----------------

__global__ void k_prefix(const int* __restrict__ num, int* __restrict__ prefix) {
    if (threadIdx.x == 0) {
        int acc = 0;
        prefix[0] = 0;
        for (int g = 0; g < G_GRAPHS; ++g) { acc += num[g]; prefix[g + 1] = acc; }
    }
}

__global__ void k_gid(const int* __restrict__ prefix, int* __restrict__ gid) {
    int e = blockIdx.x * blockDim.x + threadIdx.x;
    if (e >= E_EDGES) return;
    int lo = 0, hi = G_GRAPHS;
    while (hi - lo > 1) {
        int mid = (lo + hi) >> 1;
        if (e >= prefix[mid]) lo = mid; else hi = mid;
    }
    gid[e] = lo;
}

// dst[n*Ks + k] = (f16) src[k*Ns + n]   (transpose + fp32->f16)
__global__ void k_transpose(const float* __restrict__ src, _Float16* __restrict__ dst,
                            int Ks, int Ns) {
    long total = (long)Ks * Ns;
    for (long idx = (long)blockIdx.x * blockDim.x + threadIdx.x; idx < total;
         idx += (long)gridDim.x * blockDim.x) {
        int n = (int)(idx / Ks);
        int k = (int)(idx - (long)n * Ks);
        dst[idx] = (_Float16)src[(long)k * Ns + n];
    }
}

// ---------------- GEMM1: gather-fused  [E,1408] x W1t -> relu -> h1[E,512] f16 ----------------
// BM=128 BN=128 BK=64, 256 thr = 4 waves (2x2), wave tile 64x64, mfma 16x16x32 f16
// T14 reg-prefetch: issue tile kt+1 loads before computing tile kt.
// grid = dim3(bn=4, bm=800): sibling bn-blocks dispatch adjacently -> gather L3 reuse.

__global__ __launch_bounds__(256) void k_gemm1(
    const float* __restrict__ feat, const float* __restrict__ nodes,
    const float* __restrict__ gfeat, const int* __restrict__ ind,
    const int* __restrict__ gid, const _Float16* __restrict__ Wt,
    const float* __restrict__ bias, _Float16* __restrict__ out) {
    __shared__ __align__(16) _Float16 As[128][72];
    __shared__ __align__(16) _Float16 Bs[128][72];
    const int t = threadIdx.x;
    const int bn = blockIdx.x, bm = blockIdx.y;
    const int w = t >> 6, lane = t & 63;
    const int wr = w >> 1, wc = w & 1, lr = lane & 15, lk = lane >> 4;
    const int n0 = bn * 128;
    const int r = t >> 1;            // A/B staging: 2 threads per row
    const int cb = (t & 1) * 32;     // 32 elements each
    const int e = bm * 128 + r;

    const int4 iv = *reinterpret_cast<const int4*>(ind + (size_t)e * KNB);
    const int g = gid[e];

    f32x4 acc[4][4];
#pragma unroll
    for (int m = 0; m < 4; m++)
#pragma unroll
        for (int n = 0; n < 4; n++) acc[m][n] = (f32x4)0.f;

    float4 pa[8];
    half8 pb[4];

    auto issue = [&](int kt) {
        const float* s;
        if (kt < 4) {
            s = feat + (size_t)e * D_EDGE + kt * 64;
        } else if (kt < 20) {
            int j = (kt - 4) >> 2;
            int c0 = ((kt - 4) & 3) * 64;
            int nidx = j == 0 ? iv.x : j == 1 ? iv.y : j == 2 ? iv.z : iv.w;
            s = nodes + (size_t)nidx * D_NODE + c0;
        } else {
            s = gfeat + (size_t)g * D_GLOB + (kt - 20) * 64;
        }
        s += cb;
#pragma unroll
        for (int i = 0; i < 8; i++) pa[i] = reinterpret_cast<const float4*>(s)[i];
        const _Float16* wsrc = Wt + (size_t)(n0 + r) * D_IN + kt * 64 + cb;
#pragma unroll
        for (int i = 0; i < 4; i++) pb[i] = reinterpret_cast<const half8*>(wsrc)[i];
    };
    auto commit = [&]() {
#pragma unroll
        for (int i = 0; i < 8; i++) {
            half4v h;
            h.x = (_Float16)pa[i].x; h.y = (_Float16)pa[i].y;
            h.z = (_Float16)pa[i].z; h.w = (_Float16)pa[i].w;
            *reinterpret_cast<half4v*>(&As[r][cb + i * 4]) = h;
        }
#pragma unroll
        for (int i = 0; i < 4; i++)
            *reinterpret_cast<half8*>(&Bs[r][cb + i * 8]) = pb[i];
    };

    issue(0);
    commit();
    __syncthreads();
    for (int kt = 0; kt < 22; ++kt) {
        if (kt < 21) issue(kt + 1);
#pragma unroll
        for (int kk = 0; kk < 2; kk++) {
            half8 a[4], b[4];
#pragma unroll
            for (int m = 0; m < 4; m++)
                a[m] = *reinterpret_cast<half8*>(&As[wr * 64 + m * 16 + lr][kk * 32 + lk * 8]);
#pragma unroll
            for (int n = 0; n < 4; n++)
                b[n] = *reinterpret_cast<half8*>(&Bs[wc * 64 + n * 16 + lr][kk * 32 + lk * 8]);
#pragma unroll
            for (int m = 0; m < 4; m++)
#pragma unroll
                for (int n = 0; n < 4; n++)
                    acc[m][n] = __builtin_amdgcn_mfma_f32_16x16x32_f16(a[m], b[n], acc[m][n], 0, 0, 0);
        }
        __syncthreads();
        if (kt < 21) { commit(); __syncthreads(); }
    }
    // ---- epilogue: relu(acc + bias) -> f16 ----
#pragma unroll
    for (int n = 0; n < 4; n++) {
        int col = n0 + wc * 64 + n * 16 + lr;
        float bv = bias[col];
#pragma unroll
        for (int m = 0; m < 4; m++) {
            int rbase = bm * 128 + wr * 64 + m * 16 + lk * 4;
#pragma unroll
            for (int q = 0; q < 4; q++) {
                float v = acc[m][n][q] + bv;
                v = v > 0.f ? v : 0.f;
                out[(size_t)(rbase + q) * H1D + col] = (_Float16)v;
            }
        }
    }
}

// ---------------- GEMM2: h1[E,512] x W2t -> relu -> h2[E,512] f16 ----------------

__global__ __launch_bounds__(256) void k_gemm2(
    const _Float16* __restrict__ A, const _Float16* __restrict__ Wt,
    const float* __restrict__ bias, _Float16* __restrict__ out) {
    __shared__ __align__(16) _Float16 As[128][72];
    __shared__ __align__(16) _Float16 Bs[128][72];
    const int t = threadIdx.x;
    const int bn = blockIdx.x, bm = blockIdx.y;
    const int w = t >> 6, lane = t & 63;
    const int wr = w >> 1, wc = w & 1, lr = lane & 15, lk = lane >> 4;
    const int n0 = bn * 128;
    const int r = t >> 1;
    const int cb = (t & 1) * 32;

    f32x4 acc[4][4];
#pragma unroll
    for (int m = 0; m < 4; m++)
#pragma unroll
        for (int n = 0; n < 4; n++) acc[m][n] = (f32x4)0.f;

    half8 pa[4], pb[4];
    const _Float16* asrc0 = A + (size_t)(bm * 128 + r) * H1D + cb;
    const _Float16* bsrc0 = Wt + (size_t)(n0 + r) * H1D + cb;

    auto issue = [&](int kt) {
#pragma unroll
        for (int i = 0; i < 4; i++) pa[i] = reinterpret_cast<const half8*>(asrc0 + kt * 64)[i];
#pragma unroll
        for (int i = 0; i < 4; i++) pb[i] = reinterpret_cast<const half8*>(bsrc0 + kt * 64)[i];
    };
    auto commit = [&]() {
#pragma unroll
        for (int i = 0; i < 4; i++) {
            *reinterpret_cast<half8*>(&As[r][cb + i * 8]) = pa[i];
            *reinterpret_cast<half8*>(&Bs[r][cb + i * 8]) = pb[i];
        }
    };

    issue(0);
    commit();
    __syncthreads();
    for (int kt = 0; kt < 8; ++kt) {
        if (kt < 7) issue(kt + 1);
#pragma unroll
        for (int kk = 0; kk < 2; kk++) {
            half8 a[4], b[4];
#pragma unroll
            for (int m = 0; m < 4; m++)
                a[m] = *reinterpret_cast<half8*>(&As[wr * 64 + m * 16 + lr][kk * 32 + lk * 8]);
#pragma unroll
            for (int n = 0; n < 4; n++)
                b[n] = *reinterpret_cast<half8*>(&Bs[wc * 64 + n * 16 + lr][kk * 32 + lk * 8]);
#pragma unroll
            for (int m = 0; m < 4; m++)
#pragma unroll
                for (int n = 0; n < 4; n++)
                    acc[m][n] = __builtin_amdgcn_mfma_f32_16x16x32_f16(a[m], b[n], acc[m][n], 0, 0, 0);
        }
        __syncthreads();
        if (kt < 7) { commit(); __syncthreads(); }
    }
#pragma unroll
    for (int n = 0; n < 4; n++) {
        int col = n0 + wc * 64 + n * 16 + lr;
        float bv = bias[col];
#pragma unroll
        for (int m = 0; m < 4; m++) {
            int rbase = bm * 128 + wr * 64 + m * 16 + lk * 4;
#pragma unroll
            for (int q = 0; q < 4; q++) {
                float v = acc[m][n][q] + bv;
                v = v > 0.f ? v : 0.f;
                out[(size_t)(rbase + q) * H2D + col] = (_Float16)v;
            }
        }
    }
}

// ---------------- GEMM3 + sigmoid + LayerNorm: h2[E,512] x W3t -> out[E,256] f32 ----------------
// BM=128 BN=256 (full width so LN lives in-block), 512 thr = 8 waves (2x4)

__global__ __launch_bounds__(512) void k_gemm3_ln(
    const _Float16* __restrict__ A, const _Float16* __restrict__ Wt,
    const float* __restrict__ bias, const float* __restrict__ gamma,
    const float* __restrict__ beta, float* __restrict__ out) {
    __shared__ __align__(16) _Float16 As[128][72];
    __shared__ __align__(16) _Float16 Bs[256][72];
    __shared__ float red1[128][4];
    __shared__ float red2[128][4];
    __shared__ float mvmu[128];
    __shared__ float mvrs[128];
    const int t = threadIdx.x;
    const int bm = blockIdx.x;
    const int w = t >> 6, lane = t & 63;
    const int wr = w >> 2, wc = w & 3, lr = lane & 15, lk = lane >> 4;

    f32x4 acc[4][4];
#pragma unroll
    for (int m = 0; m < 4; m++)
#pragma unroll
        for (int n = 0; n < 4; n++) acc[m][n] = (f32x4)0.f;

    // A staging: 4 thr/row, 16 halves each. B staging: 2 thr/row, 32 halves each.
    const int ra = t >> 2, ca = (t & 3) * 16;
    const int rb = t >> 1, cbb = (t & 1) * 32;
    half8 pa[2], pb[4];
    const _Float16* asrc0 = A + (size_t)(bm * 128 + ra) * H2D + ca;
    const _Float16* bsrc0 = Wt + (size_t)rb * H2D + cbb;

    auto issue = [&](int kt) {
#pragma unroll
        for (int i = 0; i < 2; i++) pa[i] = reinterpret_cast<const half8*>(asrc0 + kt * 64)[i];
#pragma unroll
        for (int i = 0; i < 4; i++) pb[i] = reinterpret_cast<const half8*>(bsrc0 + kt * 64)[i];
    };
    auto commit = [&]() {
#pragma unroll
        for (int i = 0; i < 2; i++)
            *reinterpret_cast<half8*>(&As[ra][ca + i * 8]) = pa[i];
#pragma unroll
        for (int i = 0; i < 4; i++)
            *reinterpret_cast<half8*>(&Bs[rb][cbb + i * 8]) = pb[i];
    };

    issue(0);
    commit();
    __syncthreads();
    for (int kt = 0; kt < 8; ++kt) {
        if (kt < 7) issue(kt + 1);
#pragma unroll
        for (int kk = 0; kk < 2; kk++) {
            half8 a[4], b[4];
#pragma unroll
            for (int m = 0; m < 4; m++)
                a[m] = *reinterpret_cast<half8*>(&As[wr * 64 + m * 16 + lr][kk * 32 + lk * 8]);
#pragma unroll
            for (int n = 0; n < 4; n++)
                b[n] = *reinterpret_cast<half8*>(&Bs[wc * 64 + n * 16 + lr][kk * 32 + lk * 8]);
#pragma unroll
            for (int m = 0; m < 4; m++)
#pragma unroll
                for (int n = 0; n < 4; n++)
                    acc[m][n] = __builtin_amdgcn_mfma_f32_16x16x32_f16(a[m], b[n], acc[m][n], 0, 0, 0);
        }
        __syncthreads();
        if (kt < 7) { commit(); __syncthreads(); }
    }

    // bias + sigmoid (in fp32, h3 never hits HBM)
#pragma unroll
    for (int n = 0; n < 4; n++) {
        int col = wc * 64 + n * 16 + lr;
        float bv = bias[col];
#pragma unroll
        for (int m = 0; m < 4; m++)
#pragma unroll
            for (int q = 0; q < 4; q++) {
                float x = acc[m][n][q] + bv;
                acc[m][n][q] = 1.f / (1.f + __expf(-x));
            }
    }

    // LayerNorm over 256 cols: per-lane partials -> 16-lane butterfly -> cross-wave LDS
#pragma unroll
    for (int m = 0; m < 4; m++)
#pragma unroll
        for (int q = 0; q < 4; q++) {
            float s1 = 0.f, s2 = 0.f;
#pragma unroll
            for (int n = 0; n < 4; n++) {
                float x = acc[m][n][q];
                s1 += x; s2 += x * x;
            }
            s1 += __shfl_xor(s1, 1); s2 += __shfl_xor(s2, 1);
            s1 += __shfl_xor(s1, 2); s2 += __shfl_xor(s2, 2);
            s1 += __shfl_xor(s1, 4); s2 += __shfl_xor(s2, 4);
            s1 += __shfl_xor(s1, 8); s2 += __shfl_xor(s2, 8);
            if (lr == 0) {
                int row = wr * 64 + m * 16 + lk * 4 + q;
                red1[row][wc] = s1;
                red2[row][wc] = s2;
            }
        }
    __syncthreads();
    if (t < 128) {
        float s = red1[t][0] + red1[t][1] + red1[t][2] + red1[t][3];
        float ss = red2[t][0] + red2[t][1] + red2[t][2] + red2[t][3];
        float mu = s * (1.f / H3D);
        float var = ss * (1.f / H3D) - mu * mu;
        mvmu[t] = mu;
        mvrs[t] = rsqrtf(var + LN_EPS);
    }
    __syncthreads();
#pragma unroll
    for (int m = 0; m < 4; m++)
#pragma unroll
        for (int q = 0; q < 4; q++) {
            int row = wr * 64 + m * 16 + lk * 4 + q;
            float mu = mvmu[row], rs = mvrs[row];
#pragma unroll
            for (int n = 0; n < 4; n++) {
                int col = wc * 64 + n * 16 + lr;
                out[(size_t)(bm * 128 + row) * H3D + col] =
                    gamma[col] * (acc[m][n][q] - mu) * rs + beta[col];
            }
        }
}

// ---------------- launch ----------------

extern "C" void kernel_launch(void* const* d_in, const int* in_sizes, int n_in,
                              void* d_out, int out_size, void* d_ws, size_t ws_size,
                              hipStream_t stream) {
    const float* feat  = (const float*)d_in[0];
    const float* nodes = (const float*)d_in[1];
    const float* gfeat = (const float*)d_in[2];
    const int*   ind   = (const int*)d_in[3];
    const int*   num   = (const int*)d_in[4];
    const float* W1    = (const float*)d_in[5];
    const float* b1    = (const float*)d_in[6];
    const float* W2    = (const float*)d_in[7];
    const float* b2    = (const float*)d_in[8];
    const float* W3    = (const float*)d_in[9];
    const float* b3    = (const float*)d_in[10];
    const float* gamma = (const float*)d_in[11];
    const float* beta  = (const float*)d_in[12];
    float* out = (float*)d_out;

    char* ws = (char*)d_ws;
    size_t off = 0;
    auto alloc = [&](size_t bytes) {
        size_t o = off;
        off += (bytes + 255) & ~(size_t)255;
        return o;
    };
    int* prefix    = (int*)(ws + alloc((G_GRAPHS + 1) * sizeof(int)));
    int* gid       = (int*)(ws + alloc((size_t)E_EDGES * sizeof(int)));
    _Float16* W1t  = (_Float16*)(ws + alloc((size_t)H1D * D_IN * 2));
    _Float16* W2t  = (_Float16*)(ws + alloc((size_t)H2D * H1D * 2));
    _Float16* W3t  = (_Float16*)(ws + alloc((size_t)H3D * H2D * 2));
    _Float16* h1   = (_Float16*)(ws + alloc((size_t)E_EDGES * H1D * 2));
    _Float16* h2   = (_Float16*)(ws + alloc((size_t)E_EDGES * H2D * 2));
    (void)ws_size; (void)in_sizes; (void)n_in; (void)out_size;

    k_prefix<<<1, 64, 0, stream>>>(num, prefix);
    k_gid<<<(E_EDGES + 255) / 256, 256, 0, stream>>>(prefix, gid);
    k_transpose<<<1024, 256, 0, stream>>>(W1, W1t, D_IN, H1D);
    k_transpose<<<512, 256, 0, stream>>>(W2, W2t, H1D, H2D);
    k_transpose<<<256, 256, 0, stream>>>(W3, W3t, H2D, H3D);
    k_gemm1<<<dim3(H1D / 128, E_EDGES / 128), 256, 0, stream>>>(feat, nodes, gfeat, ind, gid, W1t, b1, h1);
    k_gemm2<<<dim3(H2D / 128, E_EDGES / 128), 256, 0, stream>>>(h1, W2t, b2, h2);
    k_gemm3_ln<<<E_EDGES / 128, 512, 0, stream>>>(h2, W3t, b3, gamma, beta, out);
}

// Round 3
// 737.278 us; speedup vs baseline: 1.1296x; 1.1296x over previous
//
#include <hip/hip_runtime.h>
#include <hip/hip_fp16.h>

#define E_EDGES 102400
#define N_NODES 100000
#define G_GRAPHS 64
#define D_EDGE 256
#define D_NODE 256
#define D_GLOB 128
#define KNB 4
#define D_IN 1408   // 256 + 4*256 + 128
#define H1D 512
#define H2D 512
#define H3D 256
#define LN_EPS 1e-3f

typedef _Float16 half8 __attribute__((ext_vector_type(8)));
typedef float f32x4 __attribute__((ext_vector_type(4)));

// async global->LDS, 16B per lane; LDS dest must be wave-uniform base (+ lane*16 by HW)
__device__ __forceinline__ void gload16(const void* g, void* l) {
    __builtin_amdgcn_global_load_lds((const __attribute__((address_space(1))) void*)g,
                                     (__attribute__((address_space(3))) void*)l, 16, 0, 0);
}

// ---------------- prep kernels ----------------

__global__ void k_prefix(const int* __restrict__ num, int* __restrict__ prefix) {
    if (threadIdx.x == 0) {
        int acc = 0;
        prefix[0] = 0;
        for (int g = 0; g < G_GRAPHS; ++g) { acc += num[g]; prefix[g + 1] = acc; }
    }
}

__global__ void k_gid(const int* __restrict__ prefix, int* __restrict__ gid) {
    int e = blockIdx.x * blockDim.x + threadIdx.x;
    if (e >= E_EDGES) return;
    int lo = 0, hi = G_GRAPHS;
    while (hi - lo > 1) {
        int mid = (lo + hi) >> 1;
        if (e >= prefix[mid]) lo = mid; else hi = mid;
    }
    gid[e] = lo;
}

// dst[n*Ks + k] = (f16) src[k*Ns + n]   (transpose + fp32->f16)
__global__ void k_transpose(const float* __restrict__ src, _Float16* __restrict__ dst,
                            int Ks, int Ns) {
    long total = (long)Ks * Ns;
    for (long idx = (long)blockIdx.x * blockDim.x + threadIdx.x; idx < total;
         idx += (long)gridDim.x * blockDim.x) {
        int n = (int)(idx / Ks);
        int k = (int)(idx - (long)n * Ks);
        dst[idx] = (_Float16)src[(long)k * Ns + n];
    }
}

// ---------------- gather: X[e] = concat(feat[e], nodes[ind[e][:]], gfeat[gid[e]]) as f16 ----------------
// one 16B chunk (8 halves) per thread-iteration; each source segment is 1KB+ contiguous -> coalesced

__global__ void k_gather(const float* __restrict__ feat, const float* __restrict__ nodes,
                         const float* __restrict__ gfeat, const int* __restrict__ ind,
                         const int* __restrict__ gid, _Float16* __restrict__ X) {
    const long total = (long)E_EDGES * (D_IN / 8);
    for (long c = (long)blockIdx.x * blockDim.x + threadIdx.x; c < total;
         c += (long)gridDim.x * blockDim.x) {
        int e = (int)(c / (D_IN / 8));
        int f0 = ((int)(c - (long)e * (D_IN / 8))) * 8;
        const float* s;
        if (f0 < D_EDGE) {
            s = feat + (size_t)e * D_EDGE + f0;
        } else if (f0 < D_EDGE + KNB * D_NODE) {
            int r = f0 - D_EDGE;
            s = nodes + (size_t)ind[e * KNB + (r >> 8)] * D_NODE + (r & 255);
        } else {
            s = gfeat + (size_t)gid[e] * D_GLOB + (f0 - (D_EDGE + KNB * D_NODE));
        }
        float4 u = reinterpret_cast<const float4*>(s)[0];
        float4 v = reinterpret_cast<const float4*>(s)[1];
        half8 h;
        h[0] = (_Float16)u.x; h[1] = (_Float16)u.y; h[2] = (_Float16)u.z; h[3] = (_Float16)u.w;
        h[4] = (_Float16)v.x; h[5] = (_Float16)v.y; h[6] = (_Float16)v.z; h[7] = (_Float16)v.w;
        *reinterpret_cast<half8*>(X + (size_t)e * D_IN + f0) = h;
    }
}

// ---------------- dense GEMM (m97 structure): [E,KD] x Wt[512,KD] -> relu -> out[E,512] f16 ----------------
// BM=128 BN=128 BK=64, 256 thr = 4 waves (2x2), linear LDS, global_load_lds x16 staging

template <int KD>
__global__ __launch_bounds__(256) void k_gemm_relu(
    const _Float16* __restrict__ A, const _Float16* __restrict__ Wt,
    const float* __restrict__ bias, _Float16* __restrict__ out) {
    __shared__ __align__(16) _Float16 As[128][64];
    __shared__ __align__(16) _Float16 Bs[128][64];
    const int t = threadIdx.x;
    const int bn = blockIdx.x, bm = blockIdx.y;
    const int w = t >> 6, lane = t & 63;
    const int wr = w >> 1, wc = w & 1, lr = lane & 15, lk = lane >> 4;
    const int n0 = bn * 128;

    // staging: call i stages rows i*32 + w*8 + (lane>>3), cols (lane&7)*8 .. +8
    const int srow = w * 8 + (lane >> 3);
    const int scol = (lane & 7) * 8;
    const _Float16* Ab = A + (size_t)(bm * 128 + srow) * KD + scol;
    const _Float16* Bb = Wt + (size_t)(n0 + srow) * KD + scol;

    f32x4 acc[4][4];
#pragma unroll
    for (int m = 0; m < 4; m++)
#pragma unroll
        for (int n = 0; n < 4; n++) acc[m][n] = (f32x4)0.f;

    for (int kt = 0; kt < KD / 64; ++kt) {
        const int k0 = kt * 64;
        __syncthreads();
#pragma unroll
        for (int i = 0; i < 4; i++) {
            gload16(Ab + (size_t)i * 32 * KD + k0, (char*)As + i * 4096 + w * 1024);
            gload16(Bb + (size_t)i * 32 * KD + k0, (char*)Bs + i * 4096 + w * 1024);
        }
        __syncthreads();
#pragma unroll
        for (int kk = 0; kk < 2; kk++) {
            half8 a[4], b[4];
#pragma unroll
            for (int m = 0; m < 4; m++)
                a[m] = *reinterpret_cast<half8*>(&As[wr * 64 + m * 16 + lr][kk * 32 + lk * 8]);
#pragma unroll
            for (int n = 0; n < 4; n++)
                b[n] = *reinterpret_cast<half8*>(&Bs[wc * 64 + n * 16 + lr][kk * 32 + lk * 8]);
#pragma unroll
            for (int m = 0; m < 4; m++)
#pragma unroll
                for (int n = 0; n < 4; n++)
                    acc[m][n] = __builtin_amdgcn_mfma_f32_16x16x32_f16(a[m], b[n], acc[m][n], 0, 0, 0);
        }
    }
    // epilogue: relu(acc + bias) -> f16
#pragma unroll
    for (int n = 0; n < 4; n++) {
        int col = n0 + wc * 64 + n * 16 + lr;
        float bv = bias[col];
#pragma unroll
        for (int m = 0; m < 4; m++) {
            int rbase = bm * 128 + wr * 64 + m * 16 + lk * 4;
#pragma unroll
            for (int q = 0; q < 4; q++) {
                float v = acc[m][n][q] + bv;
                v = v > 0.f ? v : 0.f;
                out[(size_t)(rbase + q) * H1D + col] = (_Float16)v;
            }
        }
    }
}

// ---------------- GEMM3 + sigmoid + LayerNorm: h2[E,512] x W3t[256,512] -> out[E,256] f32 ----------------
// BM=128 BN=256 (full width -> LN in-block), 512 thr = 8 waves (2x4), gload_lds staging

__global__ __launch_bounds__(512) void k_gemm3_ln(
    const _Float16* __restrict__ A, const _Float16* __restrict__ Wt,
    const float* __restrict__ bias, const float* __restrict__ gamma,
    const float* __restrict__ beta, float* __restrict__ out) {
    __shared__ __align__(16) _Float16 As[128][64];
    __shared__ __align__(16) _Float16 Bs[256][64];
    __shared__ float red1[128][4];
    __shared__ float red2[128][4];
    __shared__ float mvmu[128];
    __shared__ float mvrs[128];
    const int t = threadIdx.x;
    const int bm = blockIdx.x;
    const int w = t >> 6, lane = t & 63;
    const int wr = w >> 2, wc = w & 3, lr = lane & 15, lk = lane >> 4;

    // staging: 512 thr stage 8KB per call index; rows i*64 + w*8 + (lane>>3)
    const int srow = w * 8 + (lane >> 3);
    const int scol = (lane & 7) * 8;
    const _Float16* Ab = A + (size_t)(bm * 128 + srow) * H2D + scol;
    const _Float16* Bb = Wt + (size_t)srow * H2D + scol;

    f32x4 acc[4][4];
#pragma unroll
    for (int m = 0; m < 4; m++)
#pragma unroll
        for (int n = 0; n < 4; n++) acc[m][n] = (f32x4)0.f;

    for (int kt = 0; kt < 8; ++kt) {
        const int k0 = kt * 64;
        __syncthreads();
#pragma unroll
        for (int i = 0; i < 2; i++)
            gload16(Ab + (size_t)i * 64 * H2D + k0, (char*)As + i * 8192 + w * 1024);
#pragma unroll
        for (int i = 0; i < 4; i++)
            gload16(Bb + (size_t)i * 64 * H2D + k0, (char*)Bs + i * 8192 + w * 1024);
        __syncthreads();
#pragma unroll
        for (int kk = 0; kk < 2; kk++) {
            half8 a[4], b[4];
#pragma unroll
            for (int m = 0; m < 4; m++)
                a[m] = *reinterpret_cast<half8*>(&As[wr * 64 + m * 16 + lr][kk * 32 + lk * 8]);
#pragma unroll
            for (int n = 0; n < 4; n++)
                b[n] = *reinterpret_cast<half8*>(&Bs[wc * 64 + n * 16 + lr][kk * 32 + lk * 8]);
#pragma unroll
            for (int m = 0; m < 4; m++)
#pragma unroll
                for (int n = 0; n < 4; n++)
                    acc[m][n] = __builtin_amdgcn_mfma_f32_16x16x32_f16(a[m], b[n], acc[m][n], 0, 0, 0);
        }
    }

    // bias + sigmoid (fp32, h3 never hits HBM)
#pragma unroll
    for (int n = 0; n < 4; n++) {
        int col = wc * 64 + n * 16 + lr;
        float bv = bias[col];
#pragma unroll
        for (int m = 0; m < 4; m++)
#pragma unroll
            for (int q = 0; q < 4; q++) {
                float x = acc[m][n][q] + bv;
                acc[m][n][q] = 1.f / (1.f + __expf(-x));
            }
    }

    // LayerNorm over 256 cols: 16-lane butterfly -> cross-wave LDS
#pragma unroll
    for (int m = 0; m < 4; m++)
#pragma unroll
        for (int q = 0; q < 4; q++) {
            float s1 = 0.f, s2 = 0.f;
#pragma unroll
            for (int n = 0; n < 4; n++) {
                float x = acc[m][n][q];
                s1 += x; s2 += x * x;
            }
            s1 += __shfl_xor(s1, 1); s2 += __shfl_xor(s2, 1);
            s1 += __shfl_xor(s1, 2); s2 += __shfl_xor(s2, 2);
            s1 += __shfl_xor(s1, 4); s2 += __shfl_xor(s2, 4);
            s1 += __shfl_xor(s1, 8); s2 += __shfl_xor(s2, 8);
            if (lr == 0) {
                int row = wr * 64 + m * 16 + lk * 4 + q;
                red1[row][wc] = s1;
                red2[row][wc] = s2;
            }
        }
    __syncthreads();
    if (t < 128) {
        float s = red1[t][0] + red1[t][1] + red1[t][2] + red1[t][3];
        float ss = red2[t][0] + red2[t][1] + red2[t][2] + red2[t][3];
        float mu = s * (1.f / H3D);
        float var = ss * (1.f / H3D) - mu * mu;
        mvmu[t] = mu;
        mvrs[t] = rsqrtf(var + LN_EPS);
    }
    __syncthreads();
#pragma unroll
    for (int m = 0; m < 4; m++)
#pragma unroll
        for (int q = 0; q < 4; q++) {
            int row = wr * 64 + m * 16 + lk * 4 + q;
            float mu = mvmu[row], rs = mvrs[row];
#pragma unroll
            for (int n = 0; n < 4; n++) {
                int col = wc * 64 + n * 16 + lr;
                out[(size_t)(bm * 128 + row) * H3D + col] =
                    gamma[col] * (acc[m][n][q] - mu) * rs + beta[col];
            }
        }
}

// ---------------- launch ----------------

extern "C" void kernel_launch(void* const* d_in, const int* in_sizes, int n_in,
                              void* d_out, int out_size, void* d_ws, size_t ws_size,
                              hipStream_t stream) {
    const float* feat  = (const float*)d_in[0];
    const float* nodes = (const float*)d_in[1];
    const float* gfeat = (const float*)d_in[2];
    const int*   ind   = (const int*)d_in[3];
    const int*   num   = (const int*)d_in[4];
    const float* W1    = (const float*)d_in[5];
    const float* b1    = (const float*)d_in[6];
    const float* W2    = (const float*)d_in[7];
    const float* b2    = (const float*)d_in[8];
    const float* W3    = (const float*)d_in[9];
    const float* b3    = (const float*)d_in[10];
    const float* gamma = (const float*)d_in[11];
    const float* beta  = (const float*)d_in[12];
    float* out = (float*)d_out;

    char* ws = (char*)d_ws;
    size_t off = 0;
    auto alloc = [&](size_t bytes) {
        size_t o = off;
        off += (bytes + 255) & ~(size_t)255;
        return o;
    };
    int* prefix    = (int*)(ws + alloc((G_GRAPHS + 1) * sizeof(int)));
    int* gid       = (int*)(ws + alloc((size_t)E_EDGES * sizeof(int)));
    _Float16* W1t  = (_Float16*)(ws + alloc((size_t)H1D * D_IN * 2));
    _Float16* W2t  = (_Float16*)(ws + alloc((size_t)H2D * H1D * 2));
    _Float16* W3t  = (_Float16*)(ws + alloc((size_t)H3D * H2D * 2));
    _Float16* X    = (_Float16*)(ws + alloc((size_t)E_EDGES * D_IN * 2));
    _Float16* h1   = (_Float16*)(ws + alloc((size_t)E_EDGES * H1D * 2));
    _Float16* h2   = X;  // X dead after GEMM1; alias to save workspace
    (void)ws_size; (void)in_sizes; (void)n_in; (void)out_size;

    k_prefix<<<1, 64, 0, stream>>>(num, prefix);
    k_gid<<<(E_EDGES + 255) / 256, 256, 0, stream>>>(prefix, gid);
    k_transpose<<<1024, 256, 0, stream>>>(W1, W1t, D_IN, H1D);
    k_transpose<<<512, 256, 0, stream>>>(W2, W2t, H1D, H2D);
    k_transpose<<<256, 256, 0, stream>>>(W3, W3t, H2D, H3D);
    k_gather<<<2048, 256, 0, stream>>>(feat, nodes, gfeat, ind, gid, X);
    k_gemm_relu<D_IN><<<dim3(H1D / 128, E_EDGES / 128), 256, 0, stream>>>(X, W1t, b1, h1);
    k_gemm_relu<H1D><<<dim3(H2D / 128, E_EDGES / 128), 256, 0, stream>>>(h1, W2t, b2, h2);
    k_gemm3_ln<<<E_EDGES / 128, 512, 0, stream>>>(h2, W3t, b3, gamma, beta, out);
}

// Round 5
// 629.863 us; speedup vs baseline: 1.3222x; 1.1705x over previous
//
#include <hip/hip_runtime.h>
#include <hip/hip_fp16.h>

#define E_EDGES 102400
#define N_NODES 100000
#define G_GRAPHS 64
#define D_EDGE 256
#define D_NODE 256
#define D_GLOB 128
#define KNB 4
#define D_IN 1408   // 256 + 4*256 + 128
#define H1D 512
#define H2D 512
#define H3D 256
#define LN_EPS 1e-3f

typedef _Float16 half8 __attribute__((ext_vector_type(8)));
typedef float f32x4 __attribute__((ext_vector_type(4)));

// async global->LDS, 16B per lane; LDS dest wave-uniform base, HW adds lane*16
__device__ __forceinline__ void gload16(const void* g, void* l) {
    __builtin_amdgcn_global_load_lds((const __attribute__((address_space(1))) void*)g,
                                     (__attribute__((address_space(3))) void*)l, 16, 0, 0);
}

// ---------------- prep kernels ----------------

__global__ void k_prefix(const int* __restrict__ num, int* __restrict__ prefix) {
    if (threadIdx.x == 0) {
        int acc = 0;
        prefix[0] = 0;
        for (int g = 0; g < G_GRAPHS; ++g) { acc += num[g]; prefix[g + 1] = acc; }
    }
}

__global__ void k_gid(const int* __restrict__ prefix, int* __restrict__ gid) {
    int e = blockIdx.x * blockDim.x + threadIdx.x;
    if (e >= E_EDGES) return;
    int lo = 0, hi = G_GRAPHS;
    while (hi - lo > 1) {
        int mid = (lo + hi) >> 1;
        if (e >= prefix[mid]) lo = mid; else hi = mid;
    }
    gid[e] = lo;
}

// dst[n*Ks + k] = (f16) src[k*Ns + n]   (transpose + fp32->f16)
__global__ void k_transpose(const float* __restrict__ src, _Float16* __restrict__ dst,
                            int Ks, int Ns) {
    long total = (long)Ks * Ns;
    for (long idx = (long)blockIdx.x * blockDim.x + threadIdx.x; idx < total;
         idx += (long)gridDim.x * blockDim.x) {
        int n = (int)(idx / Ks);
        int k = (int)(idx - (long)n * Ks);
        dst[idx] = (_Float16)src[(long)k * Ns + n];
    }
}

// f32 -> f16 elementwise, 8 elems/thread-iter
__global__ void k_cvt16(const float* __restrict__ src, _Float16* __restrict__ dst, long n8) {
    for (long i = (long)blockIdx.x * blockDim.x + threadIdx.x; i < n8;
         i += (long)gridDim.x * blockDim.x) {
        float4 u = reinterpret_cast<const float4*>(src)[i * 2];
        float4 v = reinterpret_cast<const float4*>(src)[i * 2 + 1];
        half8 h;
        h[0] = (_Float16)u.x; h[1] = (_Float16)u.y; h[2] = (_Float16)u.z; h[3] = (_Float16)u.w;
        h[4] = (_Float16)v.x; h[5] = (_Float16)v.y; h[6] = (_Float16)v.z; h[7] = (_Float16)v.w;
        reinterpret_cast<half8*>(dst)[i] = h;
    }
}

// ---------------- pipelined GEMM: [E,KD] x Wt[512,KD] -> relu -> out[E,512] f16 ----------------
// BM=128 BN=256 BK=64, 512 thr = 8 waves (2x4), per-wave 64x64.
// 3 LDS buffers (48KB each: A 16KB + B 32KB), depth-2 prefetch, counted vmcnt(6),
// raw s_barrier (1/iter). Stage at iter kt writes buf[(kt+2)%3] = buffer consumed at
// iter kt-1 (all reads done before iter kt-1's barrier) -> no clobber by construction.
// T2 swizzle: LDS linear for gload_lds; GLOBAL source col pre-permuted slot^=(row&7);
// ds_read applies same XOR. T5 setprio around MFMA clusters.
// GATHER=true: A rows assembled from feat16/nodes16/gfeat16 via per-lane global addresses.

template <int KD, bool GATHER>
__global__ __launch_bounds__(512) void k_gemm_pipe(
    const _Float16* __restrict__ A,
    const _Float16* __restrict__ feat16, const _Float16* __restrict__ nodes16,
    const _Float16* __restrict__ gfeat16,
    const int* __restrict__ ind, const int* __restrict__ gid,
    const _Float16* __restrict__ Wt,
    const float* __restrict__ bias, _Float16* __restrict__ out) {
    constexpr int NT = KD / 64;
    __shared__ __align__(16) char lds[3 * 49152];  // 144 KB

    const int t = threadIdx.x;
    const int bn = blockIdx.x, bm = blockIdx.y;
    const int n0 = bn * 256;
    const int w = t >> 6, lane = t & 63;
    const int wr = w >> 2, wc = w & 3;          // 2 x 4 wave grid
    const int lr = lane & 15, lk = lane >> 4;

    // staging geometry: per call, 512 thr cover 64 rows x 8 slots (16B each)
    const int srow = t >> 3;                    // 0..63
    const int gslot = (t & 7) ^ (srow & 7);     // pre-swizzled global slot
    const int wbase = w * 8;                    // wave-uniform row base within call

    // gather row metadata (2 A-rows per thread: c=0 -> srow, c=1 -> srow+64)
    int4 iv0, iv1;
    int g0 = 0, g1 = 0;
    int e0 = 0, e1 = 0;
    if constexpr (GATHER) {
        e0 = bm * 128 + srow;
        e1 = e0 + 64;
        iv0 = *reinterpret_cast<const int4*>(ind + (size_t)e0 * KNB);
        iv1 = *reinterpret_cast<const int4*>(ind + (size_t)e1 * KNB);
        g0 = gid[e0];
        g1 = gid[e1];
    }

    f32x4 acc[4][4];
#pragma unroll
    for (int m = 0; m < 4; m++)
#pragma unroll
        for (int n = 0; n < 4; n++) acc[m][n] = (f32x4)0.f;

    auto stage = [&](int kt, char* abuf, char* bbuf) {
        // A: 2 calls (rows c*64 + srow)
#pragma unroll
        for (int c = 0; c < 2; ++c) {
            const _Float16* src;
            if constexpr (GATHER) {
                if (kt < 4) {
                    src = feat16 + (size_t)(c ? e1 : e0) * D_EDGE + kt * 64;
                } else if (kt < 20) {
                    int j = (kt - 4) >> 2;
                    int4 iv = c ? iv1 : iv0;
                    int nidx = j == 0 ? iv.x : j == 1 ? iv.y : j == 2 ? iv.z : iv.w;
                    src = nodes16 + (size_t)nidx * D_NODE + ((kt - 4) & 3) * 64;
                } else {
                    src = gfeat16 + (size_t)(c ? g1 : g0) * D_GLOB + (kt - 20) * 64;
                }
            } else {
                src = A + (size_t)(bm * 128 + c * 64 + srow) * KD + kt * 64;
            }
            gload16(src + gslot * 8, abuf + (c * 64 + wbase) * 128);
        }
        // B: 4 calls (rows = out cols n0 + c*64 + srow)
#pragma unroll
        for (int c = 0; c < 4; ++c) {
            const _Float16* src = Wt + (size_t)(n0 + c * 64 + srow) * KD + kt * 64;
            gload16(src + gslot * 8, bbuf + (c * 64 + wbase) * 128);
        }
    };

    // prologue: stage tiles 0,1; wait tile 0 (12 issued, keep newest 6 in flight)
    stage(0, lds, lds + 16384);
    stage(1, lds + 49152, lds + 49152 + 16384);
    asm volatile("s_waitcnt vmcnt(6)" ::: "memory");
    __builtin_amdgcn_s_barrier();

    int cur = 0;
    for (int kt = 0; kt < NT; ++kt) {
        const int pf = kt + 2;
        if (pf < NT) {
            const int pb = cur == 0 ? 2 : cur - 1;  // (cur+2)%3
            stage(pf, lds + pb * 49152, lds + pb * 49152 + 16384);
        }
        // compute tile kt from buf[cur]
        const char* ab = lds + cur * 49152;
        const char* bb = ab + 16384;
#pragma unroll
        for (int kk = 0; kk < 2; ++kk) {
            half8 a[4], b[4];
#pragma unroll
            for (int m = 0; m < 4; ++m) {
                int row = wr * 64 + m * 16 + lr;
                a[m] = *reinterpret_cast<const half8*>(
                    ab + row * 128 + ((((kk << 2) | lk)) ^ (lr & 7)) * 16);
            }
#pragma unroll
            for (int n = 0; n < 4; ++n) {
                int row = wc * 64 + n * 16 + lr;
                b[n] = *reinterpret_cast<const half8*>(
                    bb + row * 128 + ((((kk << 2) | lk)) ^ (lr & 7)) * 16);
            }
            __builtin_amdgcn_s_setprio(1);
#pragma unroll
            for (int m = 0; m < 4; ++m)
#pragma unroll
                for (int n = 0; n < 4; ++n)
                    acc[m][n] = __builtin_amdgcn_mfma_f32_16x16x32_f16(a[m], b[n], acc[m][n], 0, 0, 0);
            __builtin_amdgcn_s_setprio(0);
        }
        if (pf < NT) asm volatile("s_waitcnt vmcnt(6)" ::: "memory");
        else         asm volatile("s_waitcnt vmcnt(0)" ::: "memory");
        __builtin_amdgcn_s_barrier();
        cur = cur == 2 ? 0 : cur + 1;
    }

    // epilogue: relu(acc + bias) -> f16
#pragma unroll
    for (int n = 0; n < 4; ++n) {
        int col = n0 + wc * 64 + n * 16 + lr;
        float bv = bias[col];
#pragma unroll
        for (int m = 0; m < 4; ++m) {
            int rbase = bm * 128 + wr * 64 + m * 16 + lk * 4;
#pragma unroll
            for (int q = 0; q < 4; ++q) {
                float v = acc[m][n][q] + bv;
                v = v > 0.f ? v : 0.f;
                out[(size_t)(rbase + q) * H1D + col] = (_Float16)v;
            }
        }
    }
}

// ---------------- GEMM3 + sigmoid + LayerNorm: h2[E,512] x W3t[256,512] -> out[E,256] f32 ----------------
// BM=128 BN=256 (full width -> LN in-block), 512 thr = 8 waves (2x4), gload_lds staging

__global__ __launch_bounds__(512) void k_gemm3_ln(
    const _Float16* __restrict__ A, const _Float16* __restrict__ Wt,
    const float* __restrict__ bias, const float* __restrict__ gamma,
    const float* __restrict__ beta, float* __restrict__ out) {
    __shared__ __align__(16) _Float16 As[128][64];
    __shared__ __align__(16) _Float16 Bs[256][64];
    __shared__ float red1[128][4];
    __shared__ float red2[128][4];
    __shared__ float mvmu[128];
    __shared__ float mvrs[128];
    const int t = threadIdx.x;
    const int bm = blockIdx.x;
    const int w = t >> 6, lane = t & 63;
    const int wr = w >> 2, wc = w & 3, lr = lane & 15, lk = lane >> 4;

    const int srow = w * 8 + (lane >> 3);
    const int scol = (lane & 7) * 8;
    const _Float16* Ab = A + (size_t)(bm * 128 + srow) * H2D + scol;
    const _Float16* Bb = Wt + (size_t)srow * H2D + scol;

    f32x4 acc[4][4];
#pragma unroll
    for (int m = 0; m < 4; m++)
#pragma unroll
        for (int n = 0; n < 4; n++) acc[m][n] = (f32x4)0.f;

    for (int kt = 0; kt < 8; ++kt) {
        const int k0 = kt * 64;
        __syncthreads();
#pragma unroll
        for (int i = 0; i < 2; i++)
            gload16(Ab + (size_t)i * 64 * H2D + k0, (char*)As + i * 8192 + w * 1024);
#pragma unroll
        for (int i = 0; i < 4; i++)
            gload16(Bb + (size_t)i * 64 * H2D + k0, (char*)Bs + i * 8192 + w * 1024);
        __syncthreads();
#pragma unroll
        for (int kk = 0; kk < 2; kk++) {
            half8 a[4], b[4];
#pragma unroll
            for (int m = 0; m < 4; m++)
                a[m] = *reinterpret_cast<half8*>(&As[wr * 64 + m * 16 + lr][kk * 32 + lk * 8]);
#pragma unroll
            for (int n = 0; n < 4; n++)
                b[n] = *reinterpret_cast<half8*>(&Bs[wc * 64 + n * 16 + lr][kk * 32 + lk * 8]);
#pragma unroll
            for (int m = 0; m < 4; m++)
#pragma unroll
                for (int n = 0; n < 4; n++)
                    acc[m][n] = __builtin_amdgcn_mfma_f32_16x16x32_f16(a[m], b[n], acc[m][n], 0, 0, 0);
        }
    }

    // bias + sigmoid (fp32, h3 never hits HBM)
#pragma unroll
    for (int n = 0; n < 4; n++) {
        int col = wc * 64 + n * 16 + lr;
        float bv = bias[col];
#pragma unroll
        for (int m = 0; m < 4; m++)
#pragma unroll
            for (int q = 0; q < 4; q++) {
                float x = acc[m][n][q] + bv;
                acc[m][n][q] = 1.f / (1.f + __expf(-x));
            }
    }

    // LayerNorm over 256 cols
#pragma unroll
    for (int m = 0; m < 4; m++)
#pragma unroll
        for (int q = 0; q < 4; q++) {
            float s1 = 0.f, s2 = 0.f;
#pragma unroll
            for (int n = 0; n < 4; n++) {
                float x = acc[m][n][q];
                s1 += x; s2 += x * x;
            }
            s1 += __shfl_xor(s1, 1); s2 += __shfl_xor(s2, 1);
            s1 += __shfl_xor(s1, 2); s2 += __shfl_xor(s2, 2);
            s1 += __shfl_xor(s1, 4); s2 += __shfl_xor(s2, 4);
            s1 += __shfl_xor(s1, 8); s2 += __shfl_xor(s2, 8);
            if (lr == 0) {
                int row = wr * 64 + m * 16 + lk * 4 + q;
                red1[row][wc] = s1;
                red2[row][wc] = s2;
            }
        }
    __syncthreads();
    if (t < 128) {
        float s = red1[t][0] + red1[t][1] + red1[t][2] + red1[t][3];
        float ss = red2[t][0] + red2[t][1] + red2[t][2] + red2[t][3];
        float mu = s * (1.f / H3D);
        float var = ss * (1.f / H3D) - mu * mu;
        mvmu[t] = mu;
        mvrs[t] = rsqrtf(var + LN_EPS);
    }
    __syncthreads();
#pragma unroll
    for (int m = 0; m < 4; m++)
#pragma unroll
        for (int q = 0; q < 4; q++) {
            int row = wr * 64 + m * 16 + lk * 4 + q;
            float mu = mvmu[row], rs = mvrs[row];
#pragma unroll
            for (int n = 0; n < 4; n++) {
                int col = wc * 64 + n * 16 + lr;
                out[(size_t)(bm * 128 + row) * H3D + col] =
                    gamma[col] * (acc[m][n][q] - mu) * rs + beta[col];
            }
        }
}

// ---------------- launch ----------------

extern "C" void kernel_launch(void* const* d_in, const int* in_sizes, int n_in,
                              void* d_out, int out_size, void* d_ws, size_t ws_size,
                              hipStream_t stream) {
    const float* feat  = (const float*)d_in[0];
    const float* nodes = (const float*)d_in[1];
    const float* gfeat = (const float*)d_in[2];
    const int*   ind   = (const int*)d_in[3];
    const int*   num   = (const int*)d_in[4];
    const float* W1    = (const float*)d_in[5];
    const float* b1    = (const float*)d_in[6];
    const float* W2    = (const float*)d_in[7];
    const float* b2    = (const float*)d_in[8];
    const float* W3    = (const float*)d_in[9];
    const float* b3    = (const float*)d_in[10];
    const float* gamma = (const float*)d_in[11];
    const float* beta  = (const float*)d_in[12];
    float* out = (float*)d_out;

    char* ws = (char*)d_ws;
    size_t off = 0;
    auto alloc = [&](size_t bytes) {
        size_t o = off;
        off += (bytes + 255) & ~(size_t)255;
        return o;
    };
    int* prefix       = (int*)(ws + alloc((G_GRAPHS + 1) * sizeof(int)));
    int* gid          = (int*)(ws + alloc((size_t)E_EDGES * sizeof(int)));
    _Float16* W1t     = (_Float16*)(ws + alloc((size_t)H1D * D_IN * 2));
    _Float16* W2t     = (_Float16*)(ws + alloc((size_t)H2D * H1D * 2));
    _Float16* W3t     = (_Float16*)(ws + alloc((size_t)H3D * H2D * 2));
    _Float16* feat16  = (_Float16*)(ws + alloc((size_t)E_EDGES * D_EDGE * 2));
    _Float16* nodes16 = (_Float16*)(ws + alloc((size_t)N_NODES * D_NODE * 2));
    _Float16* gfeat16 = (_Float16*)(ws + alloc((size_t)G_GRAPHS * D_GLOB * 2));
    _Float16* h1      = (_Float16*)(ws + alloc((size_t)E_EDGES * H1D * 2));
    _Float16* h2      = (_Float16*)(ws + alloc((size_t)E_EDGES * H2D * 2));
    (void)ws_size; (void)in_sizes; (void)n_in; (void)out_size;

    k_prefix<<<1, 64, 0, stream>>>(num, prefix);
    k_gid<<<(E_EDGES + 255) / 256, 256, 0, stream>>>(prefix, gid);
    k_cvt16<<<2048, 256, 0, stream>>>(feat, feat16, (long)E_EDGES * D_EDGE / 8);
    k_cvt16<<<2048, 256, 0, stream>>>(nodes, nodes16, (long)N_NODES * D_NODE / 8);
    k_cvt16<<<16, 256, 0, stream>>>(gfeat, gfeat16, (long)G_GRAPHS * D_GLOB / 8);
    k_transpose<<<1024, 256, 0, stream>>>(W1, W1t, D_IN, H1D);
    k_transpose<<<512, 256, 0, stream>>>(W2, W2t, H1D, H2D);
    k_transpose<<<256, 256, 0, stream>>>(W3, W3t, H2D, H3D);
    k_gemm_pipe<D_IN, true><<<dim3(H1D / 256, E_EDGES / 128), 512, 0, stream>>>(
        nullptr, feat16, nodes16, gfeat16, ind, gid, W1t, b1, h1);
    k_gemm_pipe<H1D, false><<<dim3(H2D / 256, E_EDGES / 128), 512, 0, stream>>>(
        h1, nullptr, nullptr, nullptr, nullptr, nullptr, W2t, b2, h2);
    k_gemm3_ln<<<E_EDGES / 128, 512, 0, stream>>>(h2, W3t, b3, gamma, beta, out);
}